// Round 9
// baseline (570.346 us; speedup 1.0000x reference)
//
#include <hip/hip_runtime.h>
#include <hip/hip_bf16.h>

typedef unsigned short u16;
typedef unsigned int u32;
typedef float f32x4 __attribute__((ext_vector_type(4)));
typedef short bf16x8 __attribute__((ext_vector_type(8)));

#define D_B 2
#define D_S 2048
#define D_D 1024
#define D_H 16
#define D_NB 32
#define D_DH 64
#define D_MLP 4096
#define LOG2E 1.4426950408889634f

// ---------- bf16 helpers ----------
__device__ __forceinline__ float bflo(u32 p) { union { u32 i; float f; } c; c.i = p << 16; return c.f; }
__device__ __forceinline__ float bfhi(u32 p) { union { u32 i; float f; } c; c.i = p & 0xffff0000u; return c.f; }
__device__ __forceinline__ u16 f2bf(float f) {
  union { float f; u32 i; } c; c.f = f;
  u32 x = c.i;
  u32 r = (x + 0x7fffu + ((x >> 16) & 1u)) >> 16;   // RNE
  return (u16)r;
}
__device__ __forceinline__ u32 pack2(float lo, float hi) {
  return (u32)f2bf(lo) | ((u32)f2bf(hi) << 16);
}
// packed f32x2 -> bf16x2 (v_cvt_pk path via hip_bf16)
__device__ __forceinline__ u32 pk_bf16(float lo, float hi) {
  __hip_bfloat162 h = __float22bfloat162_rn(make_float2(lo, hi));
  union { __hip_bfloat162 h; u32 u; } c; c.h = h; return c.u;
}
__device__ __forceinline__ void unpack8(uint4 u, float* f) {
  f[0]=bflo(u.x); f[1]=bfhi(u.x); f[2]=bflo(u.y); f[3]=bfhi(u.y);
  f[4]=bflo(u.z); f[5]=bfhi(u.z); f[6]=bflo(u.w); f[7]=bfhi(u.w);
}
__device__ __forceinline__ bf16x8 scale_frag(uint4 u, float s) {
  float f[8]; unpack8(u, f);
  uint4 r;
  r.x = pack2(f[0]*s, f[1]*s); r.y = pack2(f[2]*s, f[3]*s);
  r.z = pack2(f[4]*s, f[5]*s); r.w = pack2(f[6]*s, f[7]*s);
  union { uint4 u; bf16x8 v; } c; c.u = r; return c.v;
}
__device__ __forceinline__ bf16x8 as_frag(uint4 u) {
  union { uint4 u; bf16x8 v; } c; c.u = u; return c.v;
}
// async global->LDS, 16B per lane; LDS dest = wave-uniform base + lane*16
__device__ __forceinline__ void gl_lds16(const u16* g, u16* l) {
  __builtin_amdgcn_global_load_lds((const __attribute__((address_space(1))) void*)g,
                                   (__attribute__((address_space(3))) void*)l, 16, 0, 0);
}

// ---------- 64x64 transpose tile helper: W[K,N] f32 -> WT[N,K] bf16 ----------
__device__ __forceinline__ void tr64(const float* __restrict__ W, u16* __restrict__ WT,
                                     int K, int N, int k0, int n0, int t) {
  __shared__ float tile[64][65];
  int tx = t & 15, ty = t >> 4;
  #pragma unroll
  for (int i = 0; i < 4; i++) {
    float4 v = *reinterpret_cast<const float4*>(W + (size_t)(k0 + ty * 4 + i) * N + n0 + tx * 4);
    tile[ty * 4 + i][tx * 4 + 0] = v.x;
    tile[ty * 4 + i][tx * 4 + 1] = v.y;
    tile[ty * 4 + i][tx * 4 + 2] = v.z;
    tile[ty * 4 + i][tx * 4 + 3] = v.w;
  }
  __syncthreads();
  #pragma unroll
  for (int i = 0; i < 4; i++) {
    int n = ty * 4 + i;
    uint2 o;
    o.x = pack2(tile[tx*4+0][n], tile[tx*4+1][n]);
    o.y = pack2(tile[tx*4+2][n], tile[tx*4+3][n]);
    *reinterpret_cast<uint2*>(WT + (size_t)(n0 + n) * K + k0 + tx * 4) = o;
  }
}

// ---------- prep1: Wq/Wk/Wv/Wo transposes + zero mq/mk (1025 blocks) ----------
__global__ __launch_bounds__(256) void prep1_kernel(const float* __restrict__ Wq,
                                                    const float* __restrict__ Wk,
                                                    const float* __restrict__ Wv,
                                                    const float* __restrict__ Wo,
                                                    u16* __restrict__ wqkvT,
                                                    u16* __restrict__ woT,
                                                    float* __restrict__ mqmk) {
  int bid = blockIdx.x, t = threadIdx.x;
  if (bid >= 1024) {
    reinterpret_cast<float4*>(mqmk)[t] = make_float4(0.f, 0.f, 0.f, 0.f);
    return;
  }
  const float* W; u16* WT;
  int sub = bid & 255;
  int k0 = (sub >> 4) * 64, n0 = (sub & 15) * 64;
  if (bid < 256)      { W = Wq; WT = wqkvT; }
  else if (bid < 512) { W = Wk; WT = wqkvT + 1024 * 1024; }
  else if (bid < 768) { W = Wv; WT = wqkvT + 2048 * 1024; }
  else                { W = Wo; WT = woT; }
  tr64(W, WT, 1024, 1024, k0, n0, t);
}

// ---------- prep2: W1/W2 transposes (2048 blocks) ----------
__global__ __launch_bounds__(256) void prep2_kernel(const float* __restrict__ W1,
                                                    const float* __restrict__ W2,
                                                    u16* __restrict__ w1T,
                                                    u16* __restrict__ w2T) {
  int bid = blockIdx.x, t = threadIdx.x;
  if (bid < 1024) {
    int n0 = (bid & 63) * 64, k0 = (bid >> 6) * 64;
    tr64(W1, w1T, 1024, 4096, k0, n0, t);
  } else {
    int i = bid - 1024;
    int n0 = (i & 15) * 64, k0 = (i >> 4) * 64;
    tr64(W2, w2T, 4096, 1024, k0, n0, t);
  }
}

// ---------- LayerNorm: fp32 in, bf16 out ----------
__global__ __launch_bounds__(256) void ln_kernel(const float* __restrict__ x,
                                                 const float* __restrict__ g,
                                                 const float* __restrict__ bta,
                                                 u16* __restrict__ out) {
  int row = blockIdx.x, t = threadIdx.x;
  float4 v = reinterpret_cast<const float4*>(x + (size_t)row * D_D)[t];
  float s = v.x + v.y + v.z + v.w;
  float q = v.x*v.x + v.y*v.y + v.z*v.z + v.w*v.w;
  #pragma unroll
  for (int o = 32; o; o >>= 1) { s += __shfl_down(s, o); q += __shfl_down(q, o); }
  __shared__ float rs[4], rq[4];
  if ((t & 63) == 0) { rs[t >> 6] = s; rq[t >> 6] = q; }
  __syncthreads();
  s = rs[0] + rs[1] + rs[2] + rs[3];
  q = rq[0] + rq[1] + rq[2] + rq[3];
  float mu   = s * (1.0f / 1024.0f);
  float var  = fmaxf(q * (1.0f / 1024.0f) - mu * mu, 0.0f);
  float rstd = rsqrtf(var + 1e-6f);
  float4 gg = reinterpret_cast<const float4*>(g)[t];
  float4 bb = reinterpret_cast<const float4*>(bta)[t];
  float o0 = (v.x - mu) * rstd * gg.x + bb.x;
  float o1 = (v.y - mu) * rstd * gg.y + bb.y;
  float o2 = (v.z - mu) * rstd * gg.z + bb.z;
  float o3 = (v.w - mu) * rstd * gg.w + bb.w;
  uint2 w; w.x = pack2(o0, o1); w.y = pack2(o2, o3);
  reinterpret_cast<uint2*>(out + (size_t)row * D_D)[t] = w;
}

// ---------- MFMA GEMM 128x128 (QKV only): C = A @ Bt^T, mode-3 scatter ----------
__global__ __launch_bounds__(256, 3) void gemm_bt(const u16* __restrict__ A,
                                                  const u16* __restrict__ Bt,
                                                  u16* __restrict__ Cq,
                                                  u16* __restrict__ Ck,
                                                  u16* __restrict__ Cv,
                                                  int M, int N, int K, int ldb) {
  __shared__ u16 As[128 * 32];
  __shared__ u16 Bs[128 * 32];
  const int t = threadIdx.x, w = t >> 6, lane = t & 63;
  const int quad = lane >> 4, l16 = lane & 15;
  const int m0 = blockIdx.y * 128, n0 = blockIdx.x * 128;
  const int wm = (w >> 1) * 64, wn = (w & 1) * 64;

  f32x4 acc[4][4];
  #pragma unroll
  for (int i = 0; i < 4; i++)
    #pragma unroll
    for (int n = 0; n < 4; n++) acc[i][n] = (f32x4){0.f, 0.f, 0.f, 0.f};

  const int srow = lane >> 2, scol = (lane & 3) * 8;
  const u16* ag0 = A  + (size_t)(m0 + w * 32 + srow) * K + scol;
  const u16* ag1 = ag0 + (size_t)16 * K;
  const u16* bg0 = Bt + (size_t)(n0 + w * 32 + srow) * ldb + scol;
  const u16* bg1 = bg0 + (size_t)16 * ldb;
  u16* al0 = As + w * 1024;
  u16* bl0 = Bs + w * 1024;

  for (int k0 = 0; k0 < K; k0 += 32) {
    gl_lds16(ag0 + k0, al0);
    gl_lds16(ag1 + k0, al0 + 512);
    gl_lds16(bg0 + k0, bl0);
    gl_lds16(bg1 + k0, bl0 + 512);
    __syncthreads();
    bf16x8 af[4], bf[4];
    #pragma unroll
    for (int i = 0; i < 4; i++)
      af[i] = *reinterpret_cast<const bf16x8*>(As + (wm + i * 16 + l16) * 32 + quad * 8);
    #pragma unroll
    for (int n = 0; n < 4; n++)
      bf[n] = *reinterpret_cast<const bf16x8*>(Bs + (wn + n * 16 + l16) * 32 + quad * 8);
    #pragma unroll
    for (int i = 0; i < 4; i++)
      #pragma unroll
      for (int n = 0; n < 4; n++)
        acc[i][n] = __builtin_amdgcn_mfma_f32_16x16x32_bf16(af[i], bf[n], acc[i][n], 0, 0, 0);
    __syncthreads();
  }

  #pragma unroll
  for (int i = 0; i < 4; i++) {
    #pragma unroll
    for (int r = 0; r < 4; r++) {
      const int m = m0 + wm + i * 16 + quad * 4 + r;
      #pragma unroll
      for (int nt = 0; nt < 4; nt++) {
        const int n = n0 + wn + nt * 16 + l16;
        float v = acc[i][nt][r];
        const int sel = n >> 10, nn = n & 1023;
        const int h = nn >> 6, f = nn & 63;
        const int b = m >> 11, s = m & 2047;
        const size_t bh = (size_t)(b * D_H + h);
        if (sel == 0)      Cq[(bh * D_S + s) * 96 + f] = f2bf(v);
        else if (sel == 1) Ck[(bh * D_S + s) * 96 + f] = f2bf(v);
        else               Cv[(bh * 64 + f) * D_S + s] = f2bf(v);
      }
    }
  }
}

// ---------- MFMA GEMM 64x128 tile ----------
__global__ __launch_bounds__(256, 4) void gemm_bt64(const u16* __restrict__ A,
                                                    const u16* __restrict__ Bt,
                                                    const float* __restrict__ bias,
                                                    const float* __restrict__ resid,
                                                    void* __restrict__ C,
                                                    int M, int N, int K, int ldb,
                                                    int do_relu, int out_f32) {
  __shared__ u16 As[64 * 32];
  __shared__ u16 Bs[128 * 32];
  const int t = threadIdx.x, w = t >> 6, lane = t & 63;
  const int quad = lane >> 4, l16 = lane & 15;
  const int m0 = blockIdx.y * 64, n0 = blockIdx.x * 128;
  const int wm = (w >> 1) * 32, wn = (w & 1) * 64;

  f32x4 acc[2][4];
  #pragma unroll
  for (int i = 0; i < 2; i++)
    #pragma unroll
    for (int n = 0; n < 4; n++) acc[i][n] = (f32x4){0.f, 0.f, 0.f, 0.f};

  const int srow = lane >> 2, scol = (lane & 3) * 8;
  const u16* ag0 = A  + (size_t)(m0 + w * 16 + srow) * K + scol;
  const u16* bg0 = Bt + (size_t)(n0 + w * 32 + srow) * ldb + scol;
  const u16* bg1 = bg0 + (size_t)16 * ldb;
  u16* al0 = As + w * 512;
  u16* bl0 = Bs + w * 1024;

  for (int k0 = 0; k0 < K; k0 += 32) {
    gl_lds16(ag0 + k0, al0);
    gl_lds16(bg0 + k0, bl0);
    gl_lds16(bg1 + k0, bl0 + 512);
    __syncthreads();
    bf16x8 af[2], bf[4];
    #pragma unroll
    for (int i = 0; i < 2; i++)
      af[i] = *reinterpret_cast<const bf16x8*>(As + (wm + i * 16 + l16) * 32 + quad * 8);
    #pragma unroll
    for (int n = 0; n < 4; n++)
      bf[n] = *reinterpret_cast<const bf16x8*>(Bs + (wn + n * 16 + l16) * 32 + quad * 8);
    #pragma unroll
    for (int i = 0; i < 2; i++)
      #pragma unroll
      for (int n = 0; n < 4; n++)
        acc[i][n] = __builtin_amdgcn_mfma_f32_16x16x32_bf16(af[i], bf[n], acc[i][n], 0, 0, 0);
    __syncthreads();
  }

  #pragma unroll
  for (int i = 0; i < 2; i++) {
    #pragma unroll
    for (int r = 0; r < 4; r++) {
      const int m = m0 + wm + i * 16 + quad * 4 + r;
      #pragma unroll
      for (int nt = 0; nt < 4; nt++) {
        const int n = n0 + wn + nt * 16 + l16;
        float v = acc[i][nt][r];
        if (bias)    v += bias[n];
        if (do_relu) v  = fmaxf(v, 0.0f);
        if (resid)   v += resid[(size_t)m * N + n];
        if (out_f32) reinterpret_cast<float*>(C)[(size_t)m * N + n] = v;
        else         reinterpret_cast<u16*>(C)[(size_t)m * N + n]   = f2bf(v);
      }
    }
  }
}

// ---------- bucket softmax ----------
__global__ __launch_bounds__(256) void bucket2_kernel(u16* __restrict__ qp,
                                                      const float* __restrict__ Whq,
                                                      float* __restrict__ mq,
                                                      u16* __restrict__ kp,
                                                      const float* __restrict__ Whk,
                                                      float* __restrict__ mk) {
  const int bx = blockIdx.x;
  const int side = bx >> 8;
  u16* P        = side ? kp  : qp;
  const float* Wh = side ? Whk : Whq;
  float* acc    = side ? mk  : mq;
  const float sscale = side ? 1.0f : 0.1f * LOG2E;   // fold log2e into q-side bucket probs
  const int id = bx & 255;
  const int bh = id >> 3, chunk = id & 7;
  const int h = bh & 15;
  const int t = threadIdx.x, w = t >> 6, lane = t & 63;
  const int rsub = lane >> 5;
  const int b = lane & 31;

  __shared__ float WhL[32 * 65];
  __shared__ float qs[4][2][64];
  __shared__ float accL[32];

  #pragma unroll
  for (int i = 0; i < 8; i++) {
    int idx = t * 8 + i;
    WhL[(idx & 31) * 65 + (idx >> 5)] = Wh[h * 2048 + idx];
  }
  if (t < 32) accL[t] = 0.f;
  __syncthreads();

  float whr[64];
  #pragma unroll
  for (int i = 0; i < 16; i++) {
    float4 v = *reinterpret_cast<const float4*>(&WhL[b * 65 + i * 4]);
    whr[i*4+0] = v.x; whr[i*4+1] = v.y; whr[i*4+2] = v.z; whr[i*4+3] = v.w;
  }

  float racc = 0.f;
  const int row0 = bh * 2048 + chunk * 256;
  for (int it = 0; it < 32; it++) {
    const int rr = row0 + it * 8 + w * 2 + rsub;
    u16* qrow = P + (size_t)rr * 96;
    u32 u = *reinterpret_cast<const u32*>(qrow + b * 2);
    *reinterpret_cast<float2*>(&qs[w][rsub][b * 2]) = make_float2(bflo(u), bfhi(u));
    float s0 = 0.f, s1 = 0.f, s2 = 0.f, s3 = 0.f;
    #pragma unroll
    for (int i = 0; i < 16; i++) {
      float4 qv = *reinterpret_cast<const float4*>(&qs[w][rsub][i * 4]);
      s0 = fmaf(qv.x, whr[i*4+0], s0);
      s1 = fmaf(qv.y, whr[i*4+1], s1);
      s2 = fmaf(qv.z, whr[i*4+2], s2);
      s3 = fmaf(qv.w, whr[i*4+3], s3);
    }
    float l = (s0 + s1) + (s2 + s3);
    float m = l;
    m = fmaxf(m, __shfl_xor(m, 1));  m = fmaxf(m, __shfl_xor(m, 2));
    m = fmaxf(m, __shfl_xor(m, 4));  m = fmaxf(m, __shfl_xor(m, 8));
    m = fmaxf(m, __shfl_xor(m, 16));
    float e = __expf(fminf(l - m, 0.0f));
    float ss = e;
    ss += __shfl_xor(ss, 1);  ss += __shfl_xor(ss, 2);
    ss += __shfl_xor(ss, 4);  ss += __shfl_xor(ss, 8);
    ss += __shfl_xor(ss, 16);
    float p = e / fmaxf(ss, 1e-20f);
    qrow[64 + b] = f2bf(p * sscale);
    racc += p;
  }
  atomicAdd(&accL[b], racc);
  __syncthreads();
  if (t < 32) atomicAdd(&acc[h * D_NB + t], accL[t]);
}

// ---------- MFMA flash attention v4: S^T form, no Vs, reg-prefetch K ----------
// Wave w: qh=w&1 (32 q), kvh=w>>1 (1024 keys). Logits pre-scaled by log2e -> exp2.
// S^T = mfma(Kfrag, Qfrag): rows=key(quad*4+r), cols=q(l16) -> P write as 8 ds_write_b64
// to Ps[q][key]; PV A=Pa from Ps (m=q), B=V direct from global (n=f). LDS ~45.6KB -> 3 blk/CU.
__global__ __launch_bounds__(256, 3) void attn_kernel(const u16* __restrict__ qp,
                                                      const u16* __restrict__ kp,
                                                      const u16* __restrict__ vt,
                                                      u16* __restrict__ out) {
  const int bh = blockIdx.y;
  const int s0 = blockIdx.x * 64;
  const int h = bh & 15, b = bh >> 4;
  const int t = threadIdx.x, w = t >> 6, lane = t & 63;
  const int quad = lane >> 4, l16 = lane & 15;
  const int qh = w & 1, kvh = w >> 1;

  __shared__ u16 Ks[2][64 * 104];       // [kvh][key][feat 0..95]
  __shared__ u16 Ps[4][32 * 72];        // per-wave P [qrow][key]
  __shared__ float Laux[2][64];         // per-kvh row sums

  // Q fragments (content cols scaled by 0.125*log2e; qb cols pre-scaled in bucket2)
  bf16x8 Qf[2][3];
  #pragma unroll
  for (int m = 0; m < 2; m++) {
    const u16* qr = qp + ((size_t)bh * D_S + s0 + qh * 32 + m * 16 + l16) * 96;
    #pragma unroll
    for (int kg = 0; kg < 3; kg++) {
      uint4 u = *reinterpret_cast<const uint4*>(qr + kg * 32 + quad * 8);
      Qf[m][kg] = (kg < 2) ? scale_frag(u, 0.125f * LOG2E) : as_frag(u);
    }
  }

  f32x4 Oa[2][4];
  float lp[2];
  #pragma unroll
  for (int m = 0; m < 2; m++)
    #pragma unroll
    for (int f = 0; f < 4; f++) Oa[m][f] = (f32x4){0.f,0.f,0.f,0.f};
  lp[0] = 0.f; lp[1] = 0.f;

  // K staging map: thread -> row t>>2, seg t&3 (24 u16), both kv halves
  const int srow = t >> 2, seg = t & 3;
  const u16* kgp = kp + ((size_t)bh * D_S + srow) * 96 + seg * 24;
  u16* kd0 = &Ks[0][srow * 104 + seg * 24];
  u16* kd1 = &Ks[1][srow * 104 + seg * 24];
  const u16* vbase = vt + ((size_t)bh * 64 + l16) * D_S + kvh * 1024 + quad * 8;

  // prefetch kt=0
  uint4 kr0[3], kr1[3];
  {
    const u16* ka = kgp;
    const u16* kb = kgp + (size_t)1024 * 96;
    #pragma unroll
    for (int j = 0; j < 3; j++) {
      kr0[j] = *reinterpret_cast<const uint4*>(ka + j * 8);
      kr1[j] = *reinterpret_cast<const uint4*>(kb + j * 8);
    }
  }

  for (int kt = 0; kt < 16; kt++) {
    __syncthreads();                    // prior iter's LDS reads done
    #pragma unroll
    for (int j = 0; j < 3; j++) {
      *reinterpret_cast<uint4*>(kd0 + j * 8) = kr0[j];
      *reinterpret_cast<uint4*>(kd1 + j * 8) = kr1[j];
    }
    if (kt < 15) {
      const u16* ka = kgp + (size_t)((kt + 1) * 64) * 96;
      const u16* kb = kgp + (size_t)(1024 + (kt + 1) * 64) * 96;
      #pragma unroll
      for (int j = 0; j < 3; j++) {
        kr0[j] = *reinterpret_cast<const uint4*>(ka + j * 8);
        kr1[j] = *reinterpret_cast<const uint4*>(kb + j * 8);
      }
    }
    __syncthreads();                    // staging visible

    // issue V B-frag loads early (latency covered by QK + exp)
    bf16x8 Bv[4][2];
    #pragma unroll
    for (int ft = 0; ft < 4; ft++)
      #pragma unroll
      for (int kb2 = 0; kb2 < 2; kb2++)
        Bv[ft][kb2] = *reinterpret_cast<const bf16x8*>(vbase + (size_t)ft * 16 * D_S + kt * 64 + kb2 * 32);

    // S^T per key-tile mt: rows=key, cols=q; exp + pack + Ps write inline
    #pragma unroll
    for (int mt = 0; mt < 4; mt++) {
      bf16x8 Kf[3];
      #pragma unroll
      for (int kg = 0; kg < 3; kg++)
        Kf[kg] = *reinterpret_cast<const bf16x8*>(&Ks[kvh][(mt * 16 + l16) * 104 + kg * 32 + quad * 8]);
      #pragma unroll
      for (int nt = 0; nt < 2; nt++) {
        f32x4 ST = (f32x4){0.f,0.f,0.f,0.f};
        #pragma unroll
        for (int kg = 0; kg < 3; kg++)
          ST = __builtin_amdgcn_mfma_f32_16x16x32_bf16(Kf[kg], Qf[nt][kg], ST, 0, 0, 0);
        float e0 = exp2f(ST[0]), e1 = exp2f(ST[1]), e2 = exp2f(ST[2]), e3 = exp2f(ST[3]);
        lp[nt] += (e0 + e1) + (e2 + e3);
        uint2 pk; pk.x = pk_bf16(e0, e1); pk.y = pk_bf16(e2, e3);
        *reinterpret_cast<uint2*>(&Ps[w][(nt * 16 + l16) * 72 + mt * 16 + quad * 4]) = pk;
      }
    }
    asm volatile("s_waitcnt lgkmcnt(0)" ::: "memory");   // own P writes visible

    // PV: O[q][f] += P @ V
    #pragma unroll
    for (int nt = 0; nt < 2; nt++) {
      bf16x8 Pa[2];
      #pragma unroll
      for (int kb2 = 0; kb2 < 2; kb2++)
        Pa[kb2] = *reinterpret_cast<const bf16x8*>(&Ps[w][(nt * 16 + l16) * 72 + kb2 * 32 + quad * 8]);
      #pragma unroll
      for (int ft = 0; ft < 4; ft++)
        #pragma unroll
        for (int kb2 = 0; kb2 < 2; kb2++)
          Oa[nt][ft] = __builtin_amdgcn_mfma_f32_16x16x32_bf16(Pa[kb2], Bv[ft][kb2], Oa[nt][ft], 0, 0, 0);
    }
  }

  // reduce lp across quads (lane l16 = q holds partial over its quad's keys)
  float lpr[2];
  #pragma unroll
  for (int nt = 0; nt < 2; nt++) {
    float v = lp[nt];
    v += __shfl_xor(v, 16); v += __shfl_xor(v, 32);
    lpr[nt] = v;
  }

  __syncthreads();
  if (quad == 0) {
    Laux[kvh][qh * 32 + 0 * 16 + l16] = lpr[0];
    Laux[kvh][qh * 32 + 1 * 16 + l16] = lpr[1];
  }
  float* Ob = reinterpret_cast<float*>(&Ks[0][0]);   // 64 x 68 f32 = 17408 B overlay
  if (kvh == 1) {
    #pragma unroll
    for (int nt = 0; nt < 2; nt++)
      #pragma unroll
      for (int r = 0; r < 4; r++) {
        const int row = qh * 32 + nt * 16 + quad * 4 + r;
        #pragma unroll
        for (int ft = 0; ft < 4; ft++)
          Ob[row * 68 + ft * 16 + l16] = Oa[nt][ft][r];
      }
  }
  __syncthreads();
  if (kvh == 0) {
    #pragma unroll
    for (int nt = 0; nt < 2; nt++)
      #pragma unroll
      for (int r = 0; r < 4; r++) {
        const int row = qh * 32 + nt * 16 + quad * 4 + r;
        float ltot = Laux[0][row] + Laux[1][row];
        float inv = 1.0f / fmaxf(ltot, 1e-20f);
        #pragma unroll
        for (int ft = 0; ft < 4; ft++) {
          float val = (Oa[nt][ft][r] + Ob[row * 68 + ft * 16 + l16]) * inv;
          out[((size_t)(b * D_S + s0 + row) * D_H + h) * 64 + ft * 16 + l16] = f2bf(val);
        }
      }
  }
}

// ---------- aux loss ----------
__global__ __launch_bounds__(256) void loss_kernel(const float* __restrict__ mq,
                                                   const float* __restrict__ mk,
                                                   float* __restrict__ out) {
  int t = threadIdx.x;
  float s = 0.0f;
  for (int i = t; i < 512; i += 256) {
    float a = mq[i] * (1.0f / 4096.0f);
    float c = mk[i] * (1.0f / 4096.0f);
    s += a * a + c * c;
  }
  #pragma unroll
  for (int o = 32; o; o >>= 1) s += __shfl_xor(s, o);
  __shared__ float r[4];
  if ((t & 63) == 0) r[t >> 6] = s;
  __syncthreads();
  if (t == 0) out[0] = r[0] + r[1] + r[2] + r[3];
}

extern "C" void kernel_launch(void* const* d_in, const int* in_sizes, int n_in,
                              void* d_out, int out_size, void* d_ws, size_t ws_size,
                              hipStream_t stream) {
  const float* inp  = (const float*)d_in[0];
  const float* ln1g = (const float*)d_in[1];
  const float* ln1b = (const float*)d_in[2];
  const float* Wq   = (const float*)d_in[3];
  const float* Wk   = (const float*)d_in[4];
  const float* Wv   = (const float*)d_in[5];
  const float* Whq  = (const float*)d_in[6];
  const float* Whk  = (const float*)d_in[7];
  const float* Wo   = (const float*)d_in[8];
  const float* ln2g = (const float*)d_in[9];
  const float* ln2b = (const float*)d_in[10];
  const float* W1   = (const float*)d_in[11];
  const float* b1   = (const float*)d_in[12];
  const float* W2   = (const float*)d_in[13];
  const float* b2   = (const float*)d_in[14];
  float* out = (float*)d_out;

  char* w = (char*)d_ws;
  u16* wqkvT = (u16*)(w + 0);
  u16* woT   = (u16*)(w + 6291456);
  u16* qp    = (u16*)(w + 8388608);
  u16* kp    = (u16*)(w + 20971520);
  u16* xhat  = (u16*)(w + 33554432);
  u16* attnb = xhat;
  float* mq  = (float*)(w + 41943040);
  float* mk  = mq + 512;
  u16* yhat  = (u16*)(w + 0);
  u16* w1T   = (u16*)(w + 8388608);
  u16* w2T   = (u16*)(w + 16777216);
  u16* h1    = (u16*)(w + 25165824);
  u16* vt    = (u16*)d_out;

  prep1_kernel<<<dim3(1025), dim3(256), 0, stream>>>(Wq, Wk, Wv, Wo, wqkvT, woT, mq);
  ln_kernel<<<dim3(4096), dim3(256), 0, stream>>>(inp, ln1g, ln1b, xhat);
  gemm_bt<<<dim3(24, 32), dim3(256), 0, stream>>>(xhat, wqkvT, qp, kp, vt, 4096, 3072, 1024, 1024);
  bucket2_kernel<<<dim3(512), dim3(256), 0, stream>>>(qp, Whq, mq, kp, Whk, mk);
  attn_kernel<<<dim3(32, 32), dim3(256), 0, stream>>>(qp, kp, vt, attnb);
  prep2_kernel<<<dim3(2048), dim3(256), 0, stream>>>(W1, W2, w1T, w2T);
  gemm_bt64<<<dim3(8, 64), dim3(256), 0, stream>>>(attnb, woT, nullptr, inp,
                                                   out, 4096, 1024, 1024, 1024, 0, 1);
  ln_kernel<<<dim3(4096), dim3(256), 0, stream>>>(out, ln2g, ln2b, yhat);
  gemm_bt64<<<dim3(16, 64), dim3(256), 0, stream>>>(yhat, w1T, b1, nullptr,
                                                    h1, 4096, 2048, 1024, 1024, 1, 0);
  gemm_bt64<<<dim3(8, 64), dim3(256), 0, stream>>>(h1, w2T, b2, out,
                                                   out, 4096, 1024, 2048, 4096, 0, 1);
  gemm_bt64<<<dim3(16, 64), dim3(256), 0, stream>>>(yhat, w1T + (size_t)2048 * 1024, b1 + 2048, nullptr,
                                                    h1, 4096, 2048, 1024, 1024, 1, 0);
  gemm_bt64<<<dim3(8, 64), dim3(256), 0, stream>>>(h1, w2T + 2048, nullptr, out,
                                                   out, 4096, 1024, 2048, 4096, 0, 1);
  loss_kernel<<<dim3(1), dim3(256), 0, stream>>>(mq, mk, out + 4194304);
}